// Round 16
// baseline (94.940 us; speedup 1.0000x reference)
//
#include <hip/hip_runtime.h>
#include <hip/hip_bf16.h>

// HSA prefill R16: barrier-free, 256-thr wgs, occupancy requantized.
// R15 flat => per-wave ILP exhausted; hide residual L2 latency with TLP.
// 256-thr wg (4 waves), wave owns 4 s-blocks sequentially; occupancy quantum
// drops 8->4 waves: __launch_bounds__(256,5) = 20 waves/CU (5/SIMD, +25%)
// with VGPR cap 102 (est ~93, safe). LDS 16 KB/wg: qf SHARED 4 KB (identical
// for all waves; each wave writes the same bytes itself -> same-wave RAW,
// still zero loop barriers) + one 2.3 KB P slice per wave reused across its
// 4 blocks (same-wave WAR). kr/vr group-streaming with cross-block prefetch
// at t=3/vg=3 unchanged from R15. Epilogue: 2-round LDS tree (4 waves).

namespace {

constexpr int kLq = 256, kHQ = 32, kH = 2, kG = 16, kD = 128, kS = 16;
constexpr int kNB = 64;                    // Lkv/BS: distinct blocks per head
constexpr float kScaleLog2e = 0.08838834764831845f * 1.4426950408889634f;

constexpr int kKPackN = kH * kNB * 16 * 64;  // uint4 elems per array (2 MB)
constexpr int kPStr   = 72;                  // P row stride (shorts)
constexpr int kSStr   = 136;                 // pack LDS row stride (shorts)

// main LDS (16384 B): [0,4096) qf shared: st*1024 + lane*16
//                     [4096, 4096+4*2304) P: wave*2304 + (n*72+u)*2
//                     epilogue reuses [0,16384) as 2 slots x 2048 floats
constexpr int kQOff = 0;
constexpr int kPOff = 4096;

typedef short s16x8 __attribute__((ext_vector_type(8)));
typedef float f32x4 __attribute__((ext_vector_type(4)));

union U32BF2 { unsigned int u; __hip_bfloat162 h; };
union FragU  { uint4 u; s16x8 v; };

static __device__ inline unsigned int pk_bf16(float a, float b) {
    U32BF2 z; z.h = __float22bfloat162_rn(make_float2(a, b));
    return z.u;
}

// ---------------- pack kernel (unchanged, 512 wgs, ~5 us) ------------------
// K_packed idx = ((h*64+blk)*16 + t*4+st)*64 + lane (lane = quad*16+n)
//   holds K[u = blk*64 + t*16 + n][h][d = st*32 + quad*8 + j]
// V_packed idx = ((h*64+blk)*16 + dt*2+st)*64 + lane
//   holds V[u = blk*64 + st*32 + quad*8 + j][h][d = dt*16 + n]
__global__ __launch_bounds__(256)
void pack_kv(const float* __restrict__ k, const float* __restrict__ v,
             uint4* __restrict__ kp, uint4* __restrict__ vp)
{
    __shared__ unsigned short S_s[32 * kSStr];   // 8.7 KB bf16 [u_loc][d]

    const int bid  = blockIdx.x;                 // 0..511
    const int isV  = bid & 1;
    const int half = (bid >> 1) & 1;
    const int blk  = (bid >> 2) & 63;
    const int h    = bid >> 8;
    const int t    = threadIdx.x;
    const int lane = t & 63, n = lane & 15, quad = lane >> 4;
    const int wv   = t >> 6;                     // 0..3

    {   // coalesced load 32 rows x 128 fp32 -> bf16 LDS
        const float* src = (isV ? v : k) +
            ((size_t)(blk * 64 + half * 32) * kH + h) * kD;
        const int r0 = t >> 5, c4 = (t & 31) << 2;
        #pragma unroll
        for (int p = 0; p < 4; ++p) {
            const int r = p * 8 + r0;
            const float4 f = *(const float4*)(src + (size_t)r * (kH * kD) + c4);
            *(unsigned int*)&S_s[r * kSStr + c4]     = pk_bf16(f.x, f.y);
            *(unsigned int*)&S_s[r * kSStr + c4 + 2] = pk_bf16(f.z, f.w);
        }
    }
    __syncthreads();

    const size_t obase = (size_t)(h * 64 + blk) * 16 * 64;
    if (!isV) {
        #pragma unroll
        for (int rep = 0; rep < 2; ++rep) {
            const int cl    = wv * 2 + rep;      // 0..7
            const int t_loc = cl >> 2, st = cl & 3;
            const int c     = (2 * half + t_loc) * 4 + st;
            const int u_loc = t_loc * 16 + n;
            kp[obase + (size_t)c * 64 + lane] =
                *(const uint4*)&S_s[u_loc * kSStr + st * 32 + quad * 8];
        }
    } else {
        #pragma unroll
        for (int rep = 0; rep < 2; ++rep) {
            const int dt = wv * 2 + rep;         // 0..7
            const int c  = dt * 2 + half;
            const int d  = dt * 16 + n;
            unsigned short s[8];
            #pragma unroll
            for (int j = 0; j < 8; ++j) s[j] = S_s[(quad * 8 + j) * kSStr + d];
            uint4 val;
            val.x = s[0] | ((unsigned)s[1] << 16);
            val.y = s[2] | ((unsigned)s[3] << 16);
            val.z = s[4] | ((unsigned)s[5] << 16);
            val.w = s[6] | ((unsigned)s[7] << 16);
            vp[obase + (size_t)c * 64 + lane] = val;
        }
    }
}

// ---------------- main kernel --------------------------------------------
__global__ __launch_bounds__(256, 5)
void hsa_main(const float* __restrict__ q, const float* __restrict__ w,
              const int* __restrict__ bidx, const uint4* __restrict__ kp,
              const uint4* __restrict__ vp, float* __restrict__ out)
{
    __shared__ __align__(16) unsigned char smem[16384];   // 16 KB (see layout)

    const int bid  = blockIdx.x;                 // 0..511
    const int l    = bid >> 1;
    const int h    = bid & 1;
    const int tid  = threadIdx.x;
    const int wave = tid >> 6;                   // 0..3
    const int lane = tid & 63;
    const int n    = lane & 15;
    const int quad = lane >> 4;

    // ---- Q B-frags -> SHARED LDS copy (each wave writes identical bytes;
    //      its own reads are same-wave RAW -> no barrier needed) ----
    unsigned char* qlds = smem + kQOff + lane * 16;
    {
        const float* qb = q + ((size_t)l * kHQ + h * kG + n) * kD + quad * 8;
        #pragma unroll
        for (int st = 0; st < 4; ++st) {
            const float4 f0 = *(const float4*)(qb + st * 32);
            const float4 f1 = *(const float4*)(qb + st * 32 + 4);
            uint4 z;
            z.x = pk_bf16(f0.x, f0.y); z.y = pk_bf16(f0.z, f0.w);
            z.z = pk_bf16(f1.x, f1.y); z.w = pk_bf16(f1.z, f1.w);
            *(uint4*)(qlds + st * 1024) = z;
        }
    }

    // this wave's 4 s-blocks: s = wave*4 + j
    int   base4[4];
    float wval4[4];
    #pragma unroll
    for (int j = 0; j < 4; ++j) {
        const int s  = wave * 4 + j;
        const int bi = bidx[(size_t)(l * kH + h) * kS + s];
        wval4[j] = (bi < 0) ? 0.f : w[((size_t)l * kHQ + h * kG + n) * kS + s];
        base4[j] = (h * kNB + max(bi, 0)) * 1024;   // uint4 idx
    }

    unsigned short* Pw = (unsigned short*)(smem + kPOff + wave * 2304);

    // prologue: block 0's K group0 + V group0 in flight
    FragU kr[4], vr[4];
    #pragma unroll
    for (int st = 0; st < 4; ++st) kr[st].u = kp[base4[0] + st * 64 + lane];
    #pragma unroll
    for (int i = 0; i < 4; ++i)    vr[i].u  = vp[base4[0] + i * 64 + lane];
    __builtin_amdgcn_sched_barrier(0);

    f32x4 oacc[8];
    #pragma unroll
    for (int dt = 0; dt < 8; ++dt) oacc[dt] = (f32x4){0.f, 0.f, 0.f, 0.f};

    #pragma unroll
    for (int j = 0; j < 4; ++j) {
        // ---- scores: 4 u-tile groups, exp-as-you-go, P -> private slice ----
        float part = 0.f;
        #pragma unroll
        for (int t = 0; t < 4; ++t) {
            f32x4 sc = {0.f, 0.f, 0.f, 0.f};
            #pragma unroll
            for (int st = 0; st < 4; ++st) {
                const s16x8 aq = *(const s16x8*)(qlds + st * 1024);
                sc = __builtin_amdgcn_mfma_f32_16x16x32_bf16(kr[st].v, aq, sc, 0, 0, 0);
            }
            // refill kr: next group of this block, or next block's group 0
            if (t < 3) {
                #pragma unroll
                for (int st = 0; st < 4; ++st)
                    kr[st].u = kp[base4[j] + ((t + 1) * 4 + st) * 64 + lane];
            } else if (j < 3) {
                #pragma unroll
                for (int st = 0; st < 4; ++st)
                    kr[st].u = kp[base4[j + 1] + st * 64 + lane];
            }
            __builtin_amdgcn_sched_barrier(0);

            #pragma unroll
            for (int r = 0; r < 4; ++r) {
                sc[r] = exp2f(sc[r] * kScaleLog2e);
                part += sc[r];
            }
            const unsigned long long pq =
                ((unsigned long long)pk_bf16(sc[2], sc[3]) << 32) | pk_bf16(sc[0], sc[1]);
            *(unsigned long long*)&Pw[n * kPStr + t * 16 + quad * 4] = pq;
        }

        // ---- fully intra-wave denominator ----
        part += __shfl_xor(part, 16);
        part += __shfl_xor(part, 32);
        const float coef = wval4[j] / part;

        const s16x8 bf0 = *(const s16x8*)&Pw[n * kPStr + quad * 8];
        const s16x8 bf1 = *(const s16x8*)&Pw[n * kPStr + 32 + quad * 8];

        // ---- PV: 4 V-groups of 2 d-tiles, group-streamed ----
        const f32x4 zero = {0.f, 0.f, 0.f, 0.f};
        #pragma unroll
        for (int vg = 0; vg < 4; ++vg) {
            const int dt0 = vg * 2;
            f32x4 p0 = __builtin_amdgcn_mfma_f32_16x16x32_bf16(vr[0].v, bf0, zero, 0, 0, 0);
            p0       = __builtin_amdgcn_mfma_f32_16x16x32_bf16(vr[1].v, bf1, p0,   0, 0, 0);
            f32x4 p1 = __builtin_amdgcn_mfma_f32_16x16x32_bf16(vr[2].v, bf0, zero, 0, 0, 0);
            p1       = __builtin_amdgcn_mfma_f32_16x16x32_bf16(vr[3].v, bf1, p1,   0, 0, 0);
            // refill vr: next group of this block, or next block's group 0
            if (vg < 3) {
                #pragma unroll
                for (int i = 0; i < 4; ++i)
                    vr[i].u = vp[base4[j] + ((vg + 1) * 4 + i) * 64 + lane];
            } else if (j < 3) {
                #pragma unroll
                for (int i = 0; i < 4; ++i)
                    vr[i].u = vp[base4[j + 1] + i * 64 + lane];
            }
            __builtin_amdgcn_sched_barrier(0);

            #pragma unroll
            for (int r = 0; r < 4; ++r) {
                oacc[dt0 + 0][r] = fmaf(coef, p0[r], oacc[dt0 + 0][r]);
                oacc[dt0 + 1][r] = fmaf(coef, p1[r], oacc[dt0 + 1][r]);
            }
        }
    }

    // ---- epilogue: 2-round LDS tree-combine of 4 waves (reuses smem) ----
    __syncthreads();                       // qf/P reads done everywhere
    float* epi = (float*)smem;             // 2 slots x 2048 floats

    if (wave >= 2) {                       // round 1: waves 2,3 -> slots 0,1
        #pragma unroll
        for (int dt = 0; dt < 8; ++dt)
            *(f32x4*)&epi[(wave - 2) * 2048 + dt * 256 + lane * 4] = oacc[dt];
    }
    __syncthreads();
    if (wave < 2) {
        #pragma unroll
        for (int dt = 0; dt < 8; ++dt) {
            const f32x4 o = *(const f32x4*)&epi[wave * 2048 + dt * 256 + lane * 4];
            #pragma unroll
            for (int r = 0; r < 4; ++r) oacc[dt][r] += o[r];
        }
    }
    __syncthreads();
    if (wave == 1) {                       // round 2: wave 1 -> slot 0
        #pragma unroll
        for (int dt = 0; dt < 8; ++dt)
            *(f32x4*)&epi[dt * 256 + lane * 4] = oacc[dt];
    }
    __syncthreads();
    if (wave == 0) {
        float* ob = out + ((size_t)l * kHQ + h * kG + n) * kD;
        #pragma unroll
        for (int dt = 0; dt < 8; ++dt) {
            const f32x4 o = *(const f32x4*)&epi[dt * 256 + lane * 4];
            float4 val;
            #pragma unroll
            for (int r = 0; r < 4; ++r) (&val.x)[r] = oacc[dt][r] + o[r];
            *(float4*)(ob + dt * 16 + quad * 4) = val;
        }
    }
}

} // namespace

extern "C" void kernel_launch(void* const* d_in, const int* in_sizes, int n_in,
                              void* d_out, int out_size, void* d_ws, size_t ws_size,
                              hipStream_t stream)
{
    const float* q    = (const float*)d_in[0];
    const float* k    = (const float*)d_in[1];
    const float* v    = (const float*)d_in[2];
    const float* w    = (const float*)d_in[3];
    const int*   bidx = (const int*)d_in[4];
    float* out = (float*)d_out;

    uint4* kp = (uint4*)d_ws;                                   // 2 MB
    uint4* vp = (uint4*)((char*)d_ws + (size_t)kKPackN * 16);   // 2 MB

    pack_kv<<<dim3(512), dim3(256), 0, stream>>>(k, v, kp, vp);
    hsa_main<<<dim3(kLq * kH), dim3(256), 0, stream>>>(q, w, bidx, kp, vp, out);
}

// Round 17
// 88.083 us; speedup vs baseline: 1.0778x; 1.0778x over previous
//
#include <hip/hip_runtime.h>
#include <hip/hip_bf16.h>

// HSA prefill R17 = R15 + dual-bank V streaming (PV refill distance x2).
// R16 lesson (VGPR_Count=48): launch-bounds cap below the streaming register
// set makes the allocator re-serialize loads -> revert to 512-thr/cap-128.
// R15 audit: scores-phase refills are covered (~1 other-block group ahead),
// but PV refill distance was 1 V-group (~130 cyc) vs ~200-400 cyc L2 latency
// -> ~8 exposed stalls per block-pair. R17: vrA/vrB banks (A=groups 0,2 ->
// d-tiles {0,1,4,5}; B=groups 1,3 -> {2,3,6,7}), refill distance 2 groups
// (~300 cyc), both preloaded in the prologue (16 loads in flight, draining
// under the scores phase). Register budget ~120 <= 128 (2 wg/CU held).
// Everything else identical to R15 (interleaved scores, qf in LDS, dual P
// slices, barrier-free loop, tree-combine epilogue).

namespace {

constexpr int kLq = 256, kHQ = 32, kH = 2, kG = 16, kD = 128, kS = 16;
constexpr int kNB = 64;                    // Lkv/BS: distinct blocks per head
constexpr float kScaleLog2e = 0.08838834764831845f * 1.4426950408889634f;

constexpr int kKPackN = kH * kNB * 16 * 64;  // uint4 elems per array (2 MB)
constexpr int kPStr   = 72;                  // P row stride (shorts)
constexpr int kSStr   = 136;                 // pack LDS row stride (shorts)

// main-kernel LDS layout (bytes):
//   [0, 32768)        qf slices:  wave*4096 + st*1024 + lane*16   (epilogue reuse)
//   [32768, 69632)    P slices:   wave*4608 + blk*2304 + (n*72+u)*2
constexpr int kQOff = 0;
constexpr int kPOff = 32768;

typedef short s16x8 __attribute__((ext_vector_type(8)));
typedef float f32x4 __attribute__((ext_vector_type(4)));

union U32BF2 { unsigned int u; __hip_bfloat162 h; };
union FragU  { uint4 u; s16x8 v; };

static __device__ inline unsigned int pk_bf16(float a, float b) {
    U32BF2 z; z.h = __float22bfloat162_rn(make_float2(a, b));
    return z.u;
}

// ---------------- pack kernel (unchanged, 512 wgs, ~5 us) ------------------
// K_packed idx = ((h*64+blk)*16 + t*4+st)*64 + lane (lane = quad*16+n)
//   holds K[u = blk*64 + t*16 + n][h][d = st*32 + quad*8 + j]
// V_packed idx = ((h*64+blk)*16 + dt*2+st)*64 + lane
//   holds V[u = blk*64 + st*32 + quad*8 + j][h][d = dt*16 + n]
__global__ __launch_bounds__(256)
void pack_kv(const float* __restrict__ k, const float* __restrict__ v,
             uint4* __restrict__ kp, uint4* __restrict__ vp)
{
    __shared__ unsigned short S_s[32 * kSStr];   // 8.7 KB bf16 [u_loc][d]

    const int bid  = blockIdx.x;                 // 0..511
    const int isV  = bid & 1;
    const int half = (bid >> 1) & 1;
    const int blk  = (bid >> 2) & 63;
    const int h    = bid >> 8;
    const int t    = threadIdx.x;
    const int lane = t & 63, n = lane & 15, quad = lane >> 4;
    const int wv   = t >> 6;                     // 0..3

    {   // coalesced load 32 rows x 128 fp32 -> bf16 LDS
        const float* src = (isV ? v : k) +
            ((size_t)(blk * 64 + half * 32) * kH + h) * kD;
        const int r0 = t >> 5, c4 = (t & 31) << 2;
        #pragma unroll
        for (int p = 0; p < 4; ++p) {
            const int r = p * 8 + r0;
            const float4 f = *(const float4*)(src + (size_t)r * (kH * kD) + c4);
            *(unsigned int*)&S_s[r * kSStr + c4]     = pk_bf16(f.x, f.y);
            *(unsigned int*)&S_s[r * kSStr + c4 + 2] = pk_bf16(f.z, f.w);
        }
    }
    __syncthreads();

    const size_t obase = (size_t)(h * 64 + blk) * 16 * 64;
    if (!isV) {
        #pragma unroll
        for (int rep = 0; rep < 2; ++rep) {
            const int cl    = wv * 2 + rep;      // 0..7
            const int t_loc = cl >> 2, st = cl & 3;
            const int c     = (2 * half + t_loc) * 4 + st;
            const int u_loc = t_loc * 16 + n;
            kp[obase + (size_t)c * 64 + lane] =
                *(const uint4*)&S_s[u_loc * kSStr + st * 32 + quad * 8];
        }
    } else {
        #pragma unroll
        for (int rep = 0; rep < 2; ++rep) {
            const int dt = wv * 2 + rep;         // 0..7
            const int c  = dt * 2 + half;
            const int d  = dt * 16 + n;
            unsigned short s[8];
            #pragma unroll
            for (int j = 0; j < 8; ++j) s[j] = S_s[(quad * 8 + j) * kSStr + d];
            uint4 val;
            val.x = s[0] | ((unsigned)s[1] << 16);
            val.y = s[2] | ((unsigned)s[3] << 16);
            val.z = s[4] | ((unsigned)s[5] << 16);
            val.w = s[6] | ((unsigned)s[7] << 16);
            vp[obase + (size_t)c * 64 + lane] = val;
        }
    }
}

// ---------------- main kernel --------------------------------------------
__global__ __launch_bounds__(512, 4)
void hsa_main(const float* __restrict__ q, const float* __restrict__ w,
              const int* __restrict__ bidx, const uint4* __restrict__ kp,
              const uint4* __restrict__ vp, float* __restrict__ out)
{
    __shared__ __align__(16) unsigned char smem[69632];   // 68 KB (see layout)

    const int bid  = blockIdx.x;                 // 0..511
    const int l    = bid >> 1;
    const int h    = bid & 1;
    const int tid  = threadIdx.x;
    const int wave = tid >> 6;                   // 0..7
    const int lane = tid & 63;
    const int n    = lane & 15;
    const int quad = lane >> 4;

    // ---- Q B-frags -> per-wave LDS slice (frees 16 VGPR) ----
    unsigned char* qlds = smem + kQOff + wave * 4096 + lane * 16;
    {
        const float* qb = q + ((size_t)l * kHQ + h * kG + n) * kD + quad * 8;
        #pragma unroll
        for (int st = 0; st < 4; ++st) {
            const float4 f0 = *(const float4*)(qb + st * 32);
            const float4 f1 = *(const float4*)(qb + st * 32 + 4);
            uint4 z;
            z.x = pk_bf16(f0.x, f0.y); z.y = pk_bf16(f0.z, f0.w);
            z.z = pk_bf16(f1.x, f1.y); z.w = pk_bf16(f1.z, f1.w);
            *(uint4*)(qlds + st * 1024) = z;
        }
    }

    // this wave's 2 s-blocks A,B: s = wave*2 + {0,1}
    int   baseA, baseB;
    float wvalA, wvalB;
    {
        const int sA = wave * 2, sB = wave * 2 + 1;
        const int biA = bidx[(size_t)(l * kH + h) * kS + sA];
        const int biB = bidx[(size_t)(l * kH + h) * kS + sB];
        wvalA = (biA < 0) ? 0.f : w[((size_t)l * kHQ + h * kG + n) * kS + sA];
        wvalB = (biB < 0) ? 0.f : w[((size_t)l * kHQ + h * kG + n) * kS + sB];
        baseA = (h * kNB + max(biA, 0)) * 1024;
        baseB = (h * kNB + max(biB, 0)) * 1024;
    }

    unsigned short* PA = (unsigned short*)(smem + kPOff + wave * 4608);
    unsigned short* PB = PA + kG * kPStr;

    // prologue: kA <- A-K-g0, kB <- B-K-g0, vrA <- A-V-g0, vrB <- A-V-g1
    // (16 loads in flight; vr banks drain under the scores phase)
    FragU kA[4], kB[4], vrA[4], vrB[4];
    #pragma unroll
    for (int st = 0; st < 4; ++st) kA[st].u = kp[baseA + st * 64 + lane];
    #pragma unroll
    for (int st = 0; st < 4; ++st) kB[st].u = kp[baseB + st * 64 + lane];
    #pragma unroll
    for (int i = 0; i < 4; ++i)    vrA[i].u = vp[baseA + i * 64 + lane];
    #pragma unroll
    for (int i = 0; i < 4; ++i)    vrB[i].u = vp[baseA + (4 + i) * 64 + lane];
    __builtin_amdgcn_sched_barrier(0);

    f32x4 oacc[8];
    #pragma unroll
    for (int dt = 0; dt < 8; ++dt) oacc[dt] = (f32x4){0.f, 0.f, 0.f, 0.f};

    // ---- interleaved scores: A-t, B-t alternate (refill distance ~1 group) ----
    float partA = 0.f, partB = 0.f;
    #pragma unroll
    for (int t = 0; t < 4; ++t) {
        {   // A group t
            f32x4 sc = {0.f, 0.f, 0.f, 0.f};
            #pragma unroll
            for (int st = 0; st < 4; ++st) {
                const s16x8 aq = *(const s16x8*)(qlds + st * 1024);
                sc = __builtin_amdgcn_mfma_f32_16x16x32_bf16(kA[st].v, aq, sc, 0, 0, 0);
            }
            if (t < 3) {
                #pragma unroll
                for (int st = 0; st < 4; ++st)
                    kA[st].u = kp[baseA + ((t + 1) * 4 + st) * 64 + lane];
            }
            __builtin_amdgcn_sched_barrier(0);
            #pragma unroll
            for (int r = 0; r < 4; ++r) {
                sc[r] = exp2f(sc[r] * kScaleLog2e);
                partA += sc[r];
            }
            const unsigned long long pq =
                ((unsigned long long)pk_bf16(sc[2], sc[3]) << 32) | pk_bf16(sc[0], sc[1]);
            *(unsigned long long*)&PA[n * kPStr + t * 16 + quad * 4] = pq;
        }
        {   // B group t
            f32x4 sc = {0.f, 0.f, 0.f, 0.f};
            #pragma unroll
            for (int st = 0; st < 4; ++st) {
                const s16x8 aq = *(const s16x8*)(qlds + st * 1024);
                sc = __builtin_amdgcn_mfma_f32_16x16x32_bf16(kB[st].v, aq, sc, 0, 0, 0);
            }
            if (t < 3) {
                #pragma unroll
                for (int st = 0; st < 4; ++st)
                    kB[st].u = kp[baseB + ((t + 1) * 4 + st) * 64 + lane];
            }
            __builtin_amdgcn_sched_barrier(0);
            #pragma unroll
            for (int r = 0; r < 4; ++r) {
                sc[r] = exp2f(sc[r] * kScaleLog2e);
                partB += sc[r];
            }
            const unsigned long long pq =
                ((unsigned long long)pk_bf16(sc[2], sc[3]) << 32) | pk_bf16(sc[0], sc[1]);
            *(unsigned long long*)&PB[n * kPStr + t * 16 + quad * 4] = pq;
        }
    }

    // ---- intra-wave denominators ----
    partA += __shfl_xor(partA, 16);
    partA += __shfl_xor(partA, 32);
    partB += __shfl_xor(partB, 16);
    partB += __shfl_xor(partB, 32);
    const float coefA = wvalA / partA;
    const float coefB = wvalB / partB;

    const f32x4 zero = {0.f, 0.f, 0.f, 0.f};

    // ---- PV(A): banks alternate; refill distance = 2 V-groups ----
    {
        const s16x8 bf0 = *(const s16x8*)&PA[n * kPStr + quad * 8];
        const s16x8 bf1 = *(const s16x8*)&PA[n * kPStr + 32 + quad * 8];

        // vg0: vrA = A-g0 -> d-tiles 0,1 ; refill vrA <- A-g2
        {
            f32x4 p0 = __builtin_amdgcn_mfma_f32_16x16x32_bf16(vrA[0].v, bf0, zero, 0, 0, 0);
            p0       = __builtin_amdgcn_mfma_f32_16x16x32_bf16(vrA[1].v, bf1, p0,   0, 0, 0);
            f32x4 p1 = __builtin_amdgcn_mfma_f32_16x16x32_bf16(vrA[2].v, bf0, zero, 0, 0, 0);
            p1       = __builtin_amdgcn_mfma_f32_16x16x32_bf16(vrA[3].v, bf1, p1,   0, 0, 0);
            #pragma unroll
            for (int i = 0; i < 4; ++i) vrA[i].u = vp[baseA + (8 + i) * 64 + lane];
            __builtin_amdgcn_sched_barrier(0);
            #pragma unroll
            for (int r = 0; r < 4; ++r) {
                oacc[0][r] = fmaf(coefA, p0[r], oacc[0][r]);
                oacc[1][r] = fmaf(coefA, p1[r], oacc[1][r]);
            }
        }
        // vg1: vrB = A-g1 -> d-tiles 2,3 ; refill vrB <- A-g3
        {
            f32x4 p0 = __builtin_amdgcn_mfma_f32_16x16x32_bf16(vrB[0].v, bf0, zero, 0, 0, 0);
            p0       = __builtin_amdgcn_mfma_f32_16x16x32_bf16(vrB[1].v, bf1, p0,   0, 0, 0);
            f32x4 p1 = __builtin_amdgcn_mfma_f32_16x16x32_bf16(vrB[2].v, bf0, zero, 0, 0, 0);
            p1       = __builtin_amdgcn_mfma_f32_16x16x32_bf16(vrB[3].v, bf1, p1,   0, 0, 0);
            #pragma unroll
            for (int i = 0; i < 4; ++i) vrB[i].u = vp[baseA + (12 + i) * 64 + lane];
            __builtin_amdgcn_sched_barrier(0);
            #pragma unroll
            for (int r = 0; r < 4; ++r) {
                oacc[2][r] = fmaf(coefA, p0[r], oacc[2][r]);
                oacc[3][r] = fmaf(coefA, p1[r], oacc[3][r]);
            }
        }
        // vg2: vrA = A-g2 -> d-tiles 4,5 ; refill vrA <- B-g0
        {
            f32x4 p0 = __builtin_amdgcn_mfma_f32_16x16x32_bf16(vrA[0].v, bf0, zero, 0, 0, 0);
            p0       = __builtin_amdgcn_mfma_f32_16x16x32_bf16(vrA[1].v, bf1, p0,   0, 0, 0);
            f32x4 p1 = __builtin_amdgcn_mfma_f32_16x16x32_bf16(vrA[2].v, bf0, zero, 0, 0, 0);
            p1       = __builtin_amdgcn_mfma_f32_16x16x32_bf16(vrA[3].v, bf1, p1,   0, 0, 0);
            #pragma unroll
            for (int i = 0; i < 4; ++i) vrA[i].u = vp[baseB + i * 64 + lane];
            __builtin_amdgcn_sched_barrier(0);
            #pragma unroll
            for (int r = 0; r < 4; ++r) {
                oacc[4][r] = fmaf(coefA, p0[r], oacc[4][r]);
                oacc[5][r] = fmaf(coefA, p1[r], oacc[5][r]);
            }
        }
        // vg3: vrB = A-g3 -> d-tiles 6,7 ; refill vrB <- B-g1
        {
            f32x4 p0 = __builtin_amdgcn_mfma_f32_16x16x32_bf16(vrB[0].v, bf0, zero, 0, 0, 0);
            p0       = __builtin_amdgcn_mfma_f32_16x16x32_bf16(vrB[1].v, bf1, p0,   0, 0, 0);
            f32x4 p1 = __builtin_amdgcn_mfma_f32_16x16x32_bf16(vrB[2].v, bf0, zero, 0, 0, 0);
            p1       = __builtin_amdgcn_mfma_f32_16x16x32_bf16(vrB[3].v, bf1, p1,   0, 0, 0);
            #pragma unroll
            for (int i = 0; i < 4; ++i) vrB[i].u = vp[baseB + (4 + i) * 64 + lane];
            __builtin_amdgcn_sched_barrier(0);
            #pragma unroll
            for (int r = 0; r < 4; ++r) {
                oacc[6][r] = fmaf(coefA, p0[r], oacc[6][r]);
                oacc[7][r] = fmaf(coefA, p1[r], oacc[7][r]);
            }
        }
    }

    // ---- PV(B): same bank rotation on block B ----
    {
        const s16x8 bf0 = *(const s16x8*)&PB[n * kPStr + quad * 8];
        const s16x8 bf1 = *(const s16x8*)&PB[n * kPStr + 32 + quad * 8];

        // vg0: vrA = B-g0 -> d-tiles 0,1 ; refill vrA <- B-g2
        {
            f32x4 p0 = __builtin_amdgcn_mfma_f32_16x16x32_bf16(vrA[0].v, bf0, zero, 0, 0, 0);
            p0       = __builtin_amdgcn_mfma_f32_16x16x32_bf16(vrA[1].v, bf1, p0,   0, 0, 0);
            f32x4 p1 = __builtin_amdgcn_mfma_f32_16x16x32_bf16(vrA[2].v, bf0, zero, 0, 0, 0);
            p1       = __builtin_amdgcn_mfma_f32_16x16x32_bf16(vrA[3].v, bf1, p1,   0, 0, 0);
            #pragma unroll
            for (int i = 0; i < 4; ++i) vrA[i].u = vp[baseB + (8 + i) * 64 + lane];
            __builtin_amdgcn_sched_barrier(0);
            #pragma unroll
            for (int r = 0; r < 4; ++r) {
                oacc[0][r] = fmaf(coefB, p0[r], oacc[0][r]);
                oacc[1][r] = fmaf(coefB, p1[r], oacc[1][r]);
            }
        }
        // vg1: vrB = B-g1 -> d-tiles 2,3 ; refill vrB <- B-g3
        {
            f32x4 p0 = __builtin_amdgcn_mfma_f32_16x16x32_bf16(vrB[0].v, bf0, zero, 0, 0, 0);
            p0       = __builtin_amdgcn_mfma_f32_16x16x32_bf16(vrB[1].v, bf1, p0,   0, 0, 0);
            f32x4 p1 = __builtin_amdgcn_mfma_f32_16x16x32_bf16(vrB[2].v, bf0, zero, 0, 0, 0);
            p1       = __builtin_amdgcn_mfma_f32_16x16x32_bf16(vrB[3].v, bf1, p1,   0, 0, 0);
            #pragma unroll
            for (int i = 0; i < 4; ++i) vrB[i].u = vp[baseB + (12 + i) * 64 + lane];
            __builtin_amdgcn_sched_barrier(0);
            #pragma unroll
            for (int r = 0; r < 4; ++r) {
                oacc[2][r] = fmaf(coefB, p0[r], oacc[2][r]);
                oacc[3][r] = fmaf(coefB, p1[r], oacc[3][r]);
            }
        }
        // vg2: vrA = B-g2 -> d-tiles 4,5 (no refill)
        {
            f32x4 p0 = __builtin_amdgcn_mfma_f32_16x16x32_bf16(vrA[0].v, bf0, zero, 0, 0, 0);
            p0       = __builtin_amdgcn_mfma_f32_16x16x32_bf16(vrA[1].v, bf1, p0,   0, 0, 0);
            f32x4 p1 = __builtin_amdgcn_mfma_f32_16x16x32_bf16(vrA[2].v, bf0, zero, 0, 0, 0);
            p1       = __builtin_amdgcn_mfma_f32_16x16x32_bf16(vrA[3].v, bf1, p1,   0, 0, 0);
            #pragma unroll
            for (int r = 0; r < 4; ++r) {
                oacc[4][r] = fmaf(coefB, p0[r], oacc[4][r]);
                oacc[5][r] = fmaf(coefB, p1[r], oacc[5][r]);
            }
        }
        // vg3: vrB = B-g3 -> d-tiles 6,7 (no refill)
        {
            f32x4 p0 = __builtin_amdgcn_mfma_f32_16x16x32_bf16(vrB[0].v, bf0, zero, 0, 0, 0);
            p0       = __builtin_amdgcn_mfma_f32_16x16x32_bf16(vrB[1].v, bf1, p0,   0, 0, 0);
            f32x4 p1 = __builtin_amdgcn_mfma_f32_16x16x32_bf16(vrB[2].v, bf0, zero, 0, 0, 0);
            p1       = __builtin_amdgcn_mfma_f32_16x16x32_bf16(vrB[3].v, bf1, p1,   0, 0, 0);
            #pragma unroll
            for (int r = 0; r < 4; ++r) {
                oacc[6][r] = fmaf(coefB, p0[r], oacc[6][r]);
                oacc[7][r] = fmaf(coefB, p1[r], oacc[7][r]);
            }
        }
    }

    // ---- epilogue: 3-round LDS tree-combine (reuses qf region) ----
    __syncthreads();                       // qf reads done everywhere
    float* epi = (float*)(smem + kQOff);   // 4 slots x 2048 floats

    if (wave >= 4) {
        #pragma unroll
        for (int dt = 0; dt < 8; ++dt)
            *(f32x4*)&epi[(wave - 4) * 2048 + dt * 256 + lane * 4] = oacc[dt];
    }
    __syncthreads();
    if (wave < 4) {
        #pragma unroll
        for (int dt = 0; dt < 8; ++dt) {
            const f32x4 o = *(const f32x4*)&epi[wave * 2048 + dt * 256 + lane * 4];
            #pragma unroll
            for (int r = 0; r < 4; ++r) oacc[dt][r] += o[r];
        }
    }
    __syncthreads();
    if (wave == 2 || wave == 3) {
        #pragma unroll
        for (int dt = 0; dt < 8; ++dt)
            *(f32x4*)&epi[(wave - 2) * 2048 + dt * 256 + lane * 4] = oacc[dt];
    }
    __syncthreads();
    if (wave < 2) {
        #pragma unroll
        for (int dt = 0; dt < 8; ++dt) {
            const f32x4 o = *(const f32x4*)&epi[wave * 2048 + dt * 256 + lane * 4];
            #pragma unroll
            for (int r = 0; r < 4; ++r) oacc[dt][r] += o[r];
        }
    }
    __syncthreads();
    if (wave == 1) {
        #pragma unroll
        for (int dt = 0; dt < 8; ++dt)
            *(f32x4*)&epi[dt * 256 + lane * 4] = oacc[dt];
    }
    __syncthreads();
    if (wave == 0) {
        float* ob = out + ((size_t)l * kHQ + h * kG + n) * kD;
        #pragma unroll
        for (int dt = 0; dt < 8; ++dt) {
            const f32x4 o = *(const f32x4*)&epi[dt * 256 + lane * 4];
            float4 val;
            #pragma unroll
            for (int r = 0; r < 4; ++r) (&val.x)[r] = oacc[dt][r] + o[r];
            *(float4*)(ob + dt * 16 + quad * 4) = val;
        }
    }
}

} // namespace

extern "C" void kernel_launch(void* const* d_in, const int* in_sizes, int n_in,
                              void* d_out, int out_size, void* d_ws, size_t ws_size,
                              hipStream_t stream)
{
    const float* q    = (const float*)d_in[0];
    const float* k    = (const float*)d_in[1];
    const float* v    = (const float*)d_in[2];
    const float* w    = (const float*)d_in[3];
    const int*   bidx = (const int*)d_in[4];
    float* out = (float*)d_out;

    uint4* kp = (uint4*)d_ws;                                   // 2 MB
    uint4* vp = (uint4*)((char*)d_ws + (size_t)kKPackN * 16);   // 2 MB

    pack_kv<<<dim3(512), dim3(256), 0, stream>>>(k, v, kp, vp);
    hsa_main<<<dim3(kLq * kH), dim3(512), 0, stream>>>(q, w, bidx, kp, vp, out);
}